// Round 4
// baseline (259.921 us; speedup 1.0000x reference)
//
#include <hip/hip_runtime.h>
#include <hip/hip_bf16.h>

// LocalAttn: B=8 S=1024 E=512 H=16 D=32, rel-pos bias, NO causal mask.
// f32 inputs / f32 output. Internals bf16 for MFMA.
// R10: (a) proj REVERTED to 64x64 tile grid (6,128) — R9's 32x64 re-tile
// doubled W L2 traffic (+5us): proj is L2-BW-fed, not latency-starved.
// (b) attn: ONE 16-row strip per wave, grid 2048 -> 8 blocks/CU demanded
// (was 4, grid-limited). Anti-R8: buy latency overlap with WAVES, not
// per-wave lookahead. Per-wave VGPR drops (one qf, no em, half o/ls);
// K/V/Er traffic doubles but L2 was only ~33% used. 13 loads : 15 MFMAs.
__attribute__((unused)) typedef short bf16x8_chk;

typedef short bf16x8 __attribute__((ext_vector_type(8)));   // 8 bf16 (4 VGPRs)
typedef float f32x4 __attribute__((ext_vector_type(4)));
typedef unsigned int u32x2 __attribute__((ext_vector_type(2)));
typedef unsigned int u32x4 __attribute__((ext_vector_type(4)));

#if __has_builtin(__builtin_amdgcn_exp2f)
#define EXP2F(x) __builtin_amdgcn_exp2f(x)
#else
#define EXP2F(x) exp2f(x)
#endif

constexpr int Bb = 8, Ss = 1024, Ee = 512, Hh = 16, Dd = 32;
// log2(e)/sqrt(32): folds the 1/sqrt(D) softmax scale and exp->exp2 into Q.
#define QSCALE 0.25503486f

__device__ __forceinline__ bf16x8 ldg_frag(const __hip_bfloat16* p) {
    return *reinterpret_cast<const bf16x8*>(p);
}

// hardware packed f32->bf16 (RNE), lo in [15:0], hi in [31:16].
__device__ __forceinline__ unsigned pack_bf16(float lo, float hi) {
    unsigned r;
    asm("v_cvt_pk_bf16_f32 %0, %1, %2" : "=v"(r) : "v"(lo), "v"(hi));
    return r;
}

__device__ __forceinline__ float bperm_f(int addr, float v) {
    return __builtin_bit_cast(float,
        __builtin_amdgcn_ds_bpermute(addr, __builtin_bit_cast(int, v)));
}

// ---------------- f32 -> bf16 conversion into workspace -------------------
__global__ __launch_bounds__(256) void convert_kernel(
    const float* __restrict__ x,  const float* __restrict__ wq,
    const float* __restrict__ wk, const float* __restrict__ wv,
    const float* __restrict__ er,
    __hip_bfloat16* __restrict__ xb, __hip_bfloat16* __restrict__ wb,
    __hip_bfloat16* __restrict__ erb)
{
    const int GX = 1048576, GW = 65536, GE = 16376;  // in float4 groups
    int g = blockIdx.x * 256 + threadIdx.x;
    if (g >= GX + 3 * GW + GE) return;
    const float* src;
    __hip_bfloat16* dst;
    int rel;
    if (g < GX)               { src = x;  dst = xb;          rel = g; }
    else if (g < GX +   GW)   { src = wq; dst = wb;          rel = g - GX; }
    else if (g < GX + 2*GW)   { src = wk; dst = wb + 262144; rel = g - GX - GW; }
    else if (g < GX + 3*GW)   { src = wv; dst = wb + 524288; rel = g - GX - 2*GW; }
    else                      { src = er; dst = erb;         rel = g - GX - 3*GW; }
    const float4 v = *reinterpret_cast<const float4*>(src + (size_t)rel * 4);
    u32x2 pk;
    pk[0] = pack_bf16(v.x, v.y);
    pk[1] = pack_bf16(v.z, v.w);
    *reinterpret_cast<u32x2*>(dst + (size_t)rel * 4) = pk;
}

// ---------------- projection: Q/K/V = x @ W^T ------------------------------
// grid (6,128): WG = 64 rows x 256 cols of [Q|K|V]; wave = 64x64. (R0/R7
// geometry: W col-block read by 128 row-blocks; 32-row tiles doubled that.)
// V epilogue writes INTERLEAVED Vti: u32[d][512], slot (s>>5)*16+(s&15)
// packs the bf16 pair (V[s], V[s+16]) of each 32-block.
__global__ __launch_bounds__(256) void proj_kernel(
    const __hip_bfloat16* __restrict__ xb,   // [8192][512]
    const __hip_bfloat16* __restrict__ wb,   // [1536][512]
    __hip_bfloat16* __restrict__ Qs,   // [B][H][S][D], scaled by QSCALE
    __hip_bfloat16* __restrict__ Kh,   // [B][H][S][D]
    unsigned* __restrict__ Vt32)       // [B][H][D][512 u32] interleaved
{
    const int tid  = threadIdx.x;
    const int wave = tid >> 6;
    const int lane = tid & 63;
    const int li   = lane & 15;
    const int quad = lane >> 4;

    const int m0    = blockIdx.y * 64;
    const int nbase = blockIdx.x * 256 + wave * 64;   // multiple of 64

    f32x4 acc[4][4];
    #pragma unroll
    for (int rf = 0; rf < 4; ++rf)
        #pragma unroll
        for (int t = 0; t < 4; ++t) acc[rf][t] = f32x4{0.f, 0.f, 0.f, 0.f};

    const __hip_bfloat16* xp = xb + (size_t)(m0 + li) * Ee + quad * 8;
    const __hip_bfloat16* wp = wb + (size_t)(nbase + li) * Ee + quad * 8;

    for (int k0 = 0; k0 < Ee; k0 += 32) {
        bf16x8 a[4], bfr[4];
        #pragma unroll
        for (int rf = 0; rf < 4; ++rf) a[rf]  = ldg_frag(xp + rf * 16 * Ee + k0);
        #pragma unroll
        for (int t = 0; t < 4; ++t)    bfr[t] = ldg_frag(wp + t * 16 * Ee + k0);
        #pragma unroll
        for (int rf = 0; rf < 4; ++rf)
            #pragma unroll
            for (int t = 0; t < 4; ++t)
                acc[rf][t] = __builtin_amdgcn_mfma_f32_16x16x32_bf16(
                    a[rf], bfr[t], acc[rf][t], 0, 0, 0);
    }

    // epilogue. C layout: col = li, row = quad*4 + reg.
    const int mat = nbase >> 9;        // 0=Q 1=K 2=V (uniform per wave)
    const int nn0 = nbase & 511;
    const int bb  = m0 >> 10;          // 64-row block never straddles b
    const int sb  = m0 & 1023;
    if (mat == 2) {
        #pragma unroll
        for (int t = 0; t < 4; ++t) {
            int nn = nn0 + t * 16 + li;
            int h = nn >> 5, d = nn & 31;
            size_t base = ((size_t)(bb * Hh + h) * Dd + d) * 512
                        + (sb >> 5) * 16 + quad * 4;
            #pragma unroll
            for (int p = 0; p < 2; ++p) {      // rf pair (2p, 2p+1)
                u32x4 pk;
                #pragma unroll
                for (int r = 0; r < 4; ++r)
                    pk[r] = pack_bf16(acc[2*p][t][r], acc[2*p+1][t][r]);
                *reinterpret_cast<u32x4*>(Vt32 + base + (size_t)p * 16) = pk;
            }
        }
    } else {
        __hip_bfloat16* dst = (mat == 0) ? Qs : Kh;
        const float sc = (mat == 0) ? QSCALE : 1.0f;
        #pragma unroll
        for (int rf = 0; rf < 4; ++rf) {
            const int srow = sb + rf * 16 + quad * 4;
            #pragma unroll
            for (int t = 0; t < 4; ++t) {
                int nn = nn0 + t * 16 + li;
                int h = nn >> 5, d = nn & 31;
                size_t base = ((size_t)(bb * Hh + h) * Ss + srow) * Dd + d;
                #pragma unroll
                for (int r = 0; r < 4; r += 2) {
                    unsigned w = pack_bf16(acc[rf][t][r]     * sc,
                                           acc[rf][t][r + 1] * sc);
                    dst[base + (size_t)r * Dd] =
                        __builtin_bit_cast(__hip_bfloat16, (unsigned short)(w & 0xffffu));
                    dst[base + (size_t)(r + 1) * Dd] =
                        __builtin_bit_cast(__hip_bfloat16, (unsigned short)(w >> 16));
                }
            }
        }
    }
}

// ---------------- attention -----------------------------------------------
// grid 2048; (b,h) = blockIdx&127 (XCD-local: stride-128 blocks share
// (b,h) and land on the same XCD), ib = blockIdx>>7 in [0,16).
// Wave owns ONE 16-row Q strip; j-loop steps 64.
// Loads/iter: 4 K + 5 Er + 4 V = 13 for 15 MFMAs (13 + 2 ones-rowsum).
// Srel: band MFMA C-frags: source-side merged select (1 bpermute per
// band value). P round-trips small pb buffers (stride 20 u32).
__global__ __launch_bounds__(256) void attn_kernel(
    const __hip_bfloat16* __restrict__ Qs,
    const __hip_bfloat16* __restrict__ Kh,
    const __hip_bfloat16* __restrict__ Vt,   // bf16 view of Vti (same bytes)
    const __hip_bfloat16* __restrict__ Er,   // [2048][32] bf16 (row 2047 pad)
    float* __restrict__ out)                 // [B][S][E] f32
{
    const int tid  = threadIdx.x;
    const int wave = tid >> 6;
    const int lane = tid & 63;
    const int li   = lane & 15;
    const int quad = lane >> 4;

    const int c  = blockIdx.x & 127;
    const int b  = c >> 4;
    const int h  = c & 15;
    const int ib = blockIdx.x >> 7;          // 0..15
    const int i0 = ib * 64 + wave * 16;      // this wave's 16 rows

    const __hip_bfloat16* Qp = Qs + (size_t)(b * Hh + h) * Ss * Dd;
    const __hip_bfloat16* Kp = Kh + (size_t)(b * Hh + h) * Ss * Dd;
    const __hip_bfloat16* Vp = Vt + (size_t)(b * Hh + h) * Dd * Ss;

    __shared__ unsigned pb_lds[4][2][16 * 20];   // 10240 B total
    unsigned* pb0 = pb_lds[wave][0];   // cols 0-31
    unsigned* pb1 = pb_lds[wave][1];   // cols 32-63

    const bf16x8 qf = ldg_frag(Qp + (i0 + li) * Dd + quad * 8);

    // loop-invariant: bpermute byte-addresses and SOURCE-side band-half
    // selector. Band element (row, bc=li-row+15): lane 16*quad + (bc&15),
    // reg row&3. Src lanes with li+row>=15 provide block n, else n+1
    // (disjoint ranges -> merge at src; 1 bpermute per band value).
    // Pad row 2047 only ever lands in src lane 15's q4, never selected.
    int addr4[4];
    bool sel[4];
    #pragma unroll
    for (int r = 0; r < 4; ++r) {
        const int row = quad * 4 + r;
        addr4[r] = (16 * quad + ((li - row + 15) & 15)) * 4;
        sel[r]   = (li + row >= 15);       // this lane is a lower-block src
    }
    const int pbw = quad * 80 + li;        // pb write base (u32)
    const int pbr = li * 20 + quad * 4;    // pb read base (16B aligned)

    f32x4 o0 = f32x4{0,0,0,0}, o1 = f32x4{0,0,0,0};
    f32x4 ls = f32x4{0,0,0,0};
    const f32x4 zero = f32x4{0,0,0,0};

    bf16x8 ones;
    #pragma unroll
    for (int i = 0; i < 8; ++i) ones[i] = (short)0x3F80;   // bf16 1.0

    for (int j0 = 0; j0 < Ss; j0 += 64) {
        // ---- global loads (all L2-resident after first touch) ----
        bf16x8 k0 = ldg_frag(Kp + (j0      + li) * Dd + quad * 8);
        bf16x8 k1 = ldg_frag(Kp + (j0 + 16 + li) * Dd + quad * 8);
        bf16x8 k2 = ldg_frag(Kp + (j0 + 32 + li) * Dd + quad * 8);
        bf16x8 k3 = ldg_frag(Kp + (j0 + 48 + li) * Dd + quad * 8);
        const int rb = j0 - i0 + 1008;       // >= 0 for all (j0, i0)
        bf16x8 e0 = ldg_frag(Er + (rb      + li) * Dd + quad * 8);
        bf16x8 e1 = ldg_frag(Er + (rb + 16 + li) * Dd + quad * 8);
        bf16x8 e2 = ldg_frag(Er + (rb + 32 + li) * Dd + quad * 8);
        bf16x8 e3 = ldg_frag(Er + (rb + 48 + li) * Dd + quad * 8);
        bf16x8 e4 = ldg_frag(Er + (rb + 64 + li) * Dd + quad * 8);
        bf16x8 v0 = ldg_frag(Vp + (li     ) * Ss + j0 + quad * 8);
        bf16x8 v1 = ldg_frag(Vp + (li + 16) * Ss + j0 + quad * 8);
        bf16x8 v2 = ldg_frag(Vp + (li     ) * Ss + j0 + 32 + quad * 8);
        bf16x8 v3 = ldg_frag(Vp + (li + 16) * Ss + j0 + 32 + quad * 8);

        // ---- QK + band MFMAs ----
        __builtin_amdgcn_s_setprio(1);
        f32x4 s0 = __builtin_amdgcn_mfma_f32_16x16x32_bf16(qf, k0, zero, 0, 0, 0);
        f32x4 s1 = __builtin_amdgcn_mfma_f32_16x16x32_bf16(qf, k1, zero, 0, 0, 0);
        f32x4 s2 = __builtin_amdgcn_mfma_f32_16x16x32_bf16(qf, k2, zero, 0, 0, 0);
        f32x4 s3 = __builtin_amdgcn_mfma_f32_16x16x32_bf16(qf, k3, zero, 0, 0, 0);
        f32x4 q0 = __builtin_amdgcn_mfma_f32_16x16x32_bf16(qf, e0, zero, 0, 0, 0);
        f32x4 q1 = __builtin_amdgcn_mfma_f32_16x16x32_bf16(qf, e1, zero, 0, 0, 0);
        f32x4 q2 = __builtin_amdgcn_mfma_f32_16x16x32_bf16(qf, e2, zero, 0, 0, 0);
        f32x4 q3 = __builtin_amdgcn_mfma_f32_16x16x32_bf16(qf, e3, zero, 0, 0, 0);
        f32x4 q4 = __builtin_amdgcn_mfma_f32_16x16x32_bf16(qf, e4, zero, 0, 0, 0);
        __builtin_amdgcn_s_setprio(0);

        // ---- softmax numerator -> pb ----
        float p0[4], p1[4], p2[4], p3[4];
        #pragma unroll
        for (int r = 0; r < 4; ++r) {
            float m0 = sel[r] ? q0[r] : q1[r];
            float m1 = sel[r] ? q1[r] : q2[r];
            float m2 = sel[r] ? q2[r] : q3[r];
            float m3 = sel[r] ? q3[r] : q4[r];
            p0[r] = EXP2F(s0[r] + bperm_f(addr4[r], m0));
            p1[r] = EXP2F(s1[r] + bperm_f(addr4[r], m1));
            p2[r] = EXP2F(s2[r] + bperm_f(addr4[r], m2));
            p3[r] = EXP2F(s3[r] + bperm_f(addr4[r], m3));
        }
        #pragma unroll
        for (int r = 0; r < 4; ++r) {
            pb0[pbw + 20 * r] = pack_bf16(p0[r], p1[r]);
            pb1[pbw + 20 * r] = pack_bf16(p2[r], p3[r]);
        }

        // ---- PV + ones-rowsum ----
        bf16x8 pf0 = *reinterpret_cast<const bf16x8*>(&pb0[pbr]);
        bf16x8 pf1 = *reinterpret_cast<const bf16x8*>(&pb1[pbr]);
        __builtin_amdgcn_s_setprio(1);
        o0 = __builtin_amdgcn_mfma_f32_16x16x32_bf16(pf0, v0, o0, 0, 0, 0);
        o1 = __builtin_amdgcn_mfma_f32_16x16x32_bf16(pf0, v1, o1, 0, 0, 0);
        o0 = __builtin_amdgcn_mfma_f32_16x16x32_bf16(pf1, v2, o0, 0, 0, 0);
        o1 = __builtin_amdgcn_mfma_f32_16x16x32_bf16(pf1, v3, o1, 0, 0, 0);
        ls = __builtin_amdgcn_mfma_f32_16x16x32_bf16(pf0, ones, ls, 0, 0, 0);
        ls = __builtin_amdgcn_mfma_f32_16x16x32_bf16(pf1, ones, ls, 0, 0, 0);
        __builtin_amdgcn_s_setprio(0);
    }

    // ones-MFMA accumulated exact row sums in the same C layout as o0/o1:
    // ls[r] = sum_j P[i0+quad*4+r][j]. No cross-lane reduce needed.
    #pragma unroll
    for (int r = 0; r < 4; ++r) ls[r] = 1.0f / ls[r];
    #pragma unroll
    for (int r = 0; r < 4; ++r) {
        const int srow = i0 + quad * 4 + r;
        float* op = out + ((size_t)b * Ss + srow) * Ee + h * Dd;
        op[li]      = o0[r] * ls[r];
        op[16 + li] = o1[r] * ls[r];
    }
}

extern "C" void kernel_launch(void* const* d_in, const int* in_sizes, int n_in,
                              void* d_out, int out_size, void* d_ws, size_t ws_size,
                              hipStream_t stream) {
    const float* x  = (const float*)d_in[0];
    const float* Wq = (const float*)d_in[1];
    const float* Wk = (const float*)d_in[2];
    const float* Wv = (const float*)d_in[3];
    const float* Er = (const float*)d_in[4];
    float* out = (float*)d_out;

    // ws layout (bf16 elements; all offsets 16B-aligned)
    __hip_bfloat16* xb  = reinterpret_cast<__hip_bfloat16*>(d_ws);
    __hip_bfloat16* wbb = xb  + (size_t)8192 * 512;
    __hip_bfloat16* erb = wbb + (size_t)1536 * 512;
    __hip_bfloat16* Qs  = erb + 65536;                  // row 2047 = pad
    __hip_bfloat16* Kh  = Qs  + (size_t)Bb * Hh * Ss * Dd;
    __hip_bfloat16* Vt  = Kh  + (size_t)Bb * Hh * Ss * Dd;

    convert_kernel<<<4929, 256, 0, stream>>>(x, Wq, Wk, Wv, Er, xb, wbb, erb);
    proj_kernel<<<dim3(6, 128), 256, 0, stream>>>(
        xb, wbb, Qs, Kh, reinterpret_cast<unsigned*>(Vt));
    attn_kernel<<<dim3(2048), 256, 0, stream>>>(Qs, Kh, Vt, erb, out);
}

// Round 5
// 205.302 us; speedup vs baseline: 1.2660x; 1.2660x over previous
//
#include <hip/hip_runtime.h>
#include <hip/hip_bf16.h>

// LocalAttn: B=8 S=1024 E=512 H=16 D=32, rel-pos bias, NO causal mask.
// f32 inputs / f32 output. Internals bf16 for MFMA.
// R11: attn = R7 structure (grid 1024, 2 strips/wave) + LDS-staged K/V.
// Evidence (R10): runtime tracks VMEM request count (1.86x reqs -> 1.65x
// time) -> VMEM path is the binding pipe. The 4 waves of a block load
// IDENTICAL K/V tiles; stage them once per iter via global_load_lds
// (1KB/wave/tile), ds_read_b128 fragments back. Er window registers
// rotate across iters (slide by 64: em'=e3, e0'=e4 -> 4 new loads).
// Per wave-iter VMEM: 14 -> 6 (-57%). V staged with XOR-swizzled SOURCE
// (col ^ ((row&7)<<4)) + same XOR on read (guide #21: both-sides).
// Sync: stage -> Er loads -> __syncthreads (implicit vmcnt(0) drains own
// staging) -> compute -> __syncthreads (buffer reuse safety).
// proj/convert unchanged (R10 geometry = R7 geometry).

typedef short bf16x8 __attribute__((ext_vector_type(8)));   // 8 bf16 (4 VGPRs)
typedef float f32x4 __attribute__((ext_vector_type(4)));
typedef unsigned int u32x2 __attribute__((ext_vector_type(2)));
typedef unsigned int u32x4 __attribute__((ext_vector_type(4)));

#if __has_builtin(__builtin_amdgcn_exp2f)
#define EXP2F(x) __builtin_amdgcn_exp2f(x)
#else
#define EXP2F(x) exp2f(x)
#endif

constexpr int Bb = 8, Ss = 1024, Ee = 512, Hh = 16, Dd = 32;
// log2(e)/sqrt(32): folds the 1/sqrt(D) softmax scale and exp->exp2 into Q.
#define QSCALE 0.25503486f

__device__ __forceinline__ bf16x8 ldg_frag(const __hip_bfloat16* p) {
    return *reinterpret_cast<const bf16x8*>(p);
}

// hardware packed f32->bf16 (RNE), lo in [15:0], hi in [31:16].
__device__ __forceinline__ unsigned pack_bf16(float lo, float hi) {
    unsigned r;
    asm("v_cvt_pk_bf16_f32 %0, %1, %2" : "=v"(r) : "v"(lo), "v"(hi));
    return r;
}

__device__ __forceinline__ float bperm_f(int addr, float v) {
    return __builtin_bit_cast(float,
        __builtin_amdgcn_ds_bpermute(addr, __builtin_bit_cast(int, v)));
}

// async global->LDS, 16B/lane; LDS dest = uniform base + lane*16.
__device__ __forceinline__ void stage16(const void* g, void* l) {
    typedef const __attribute__((address_space(1))) char gch;
    typedef __attribute__((address_space(3))) char lch;
    __builtin_amdgcn_global_load_lds((gch*)g, (lch*)l, 16, 0, 0);
}

// ---------------- f32 -> bf16 conversion into workspace -------------------
__global__ __launch_bounds__(256) void convert_kernel(
    const float* __restrict__ x,  const float* __restrict__ wq,
    const float* __restrict__ wk, const float* __restrict__ wv,
    const float* __restrict__ er,
    __hip_bfloat16* __restrict__ xb, __hip_bfloat16* __restrict__ wb,
    __hip_bfloat16* __restrict__ erb)
{
    const int GX = 1048576, GW = 65536, GE = 16376;  // in float4 groups
    int g = blockIdx.x * 256 + threadIdx.x;
    if (g >= GX + 3 * GW + GE) return;
    const float* src;
    __hip_bfloat16* dst;
    int rel;
    if (g < GX)               { src = x;  dst = xb;          rel = g; }
    else if (g < GX +   GW)   { src = wq; dst = wb;          rel = g - GX; }
    else if (g < GX + 2*GW)   { src = wk; dst = wb + 262144; rel = g - GX - GW; }
    else if (g < GX + 3*GW)   { src = wv; dst = wb + 524288; rel = g - GX - 2*GW; }
    else                      { src = er; dst = erb;         rel = g - GX - 3*GW; }
    const float4 v = *reinterpret_cast<const float4*>(src + (size_t)rel * 4);
    u32x2 pk;
    pk[0] = pack_bf16(v.x, v.y);
    pk[1] = pack_bf16(v.z, v.w);
    *reinterpret_cast<u32x2*>(dst + (size_t)rel * 4) = pk;
}

// ---------------- projection: Q/K/V = x @ W^T ------------------------------
// grid (6,128): WG = 64 rows x 256 cols of [Q|K|V]; wave = 64x64.
// V epilogue writes INTERLEAVED Vti: u32[d][512], slot (s>>5)*16+(s&15)
// packs the bf16 pair (V[s], V[s+16]) of each 32-block.
__global__ __launch_bounds__(256) void proj_kernel(
    const __hip_bfloat16* __restrict__ xb,   // [8192][512]
    const __hip_bfloat16* __restrict__ wb,   // [1536][512]
    __hip_bfloat16* __restrict__ Qs,   // [B][H][S][D], scaled by QSCALE
    __hip_bfloat16* __restrict__ Kh,   // [B][H][S][D]
    unsigned* __restrict__ Vt32)       // [B][H][D][512 u32] interleaved
{
    const int tid  = threadIdx.x;
    const int wave = tid >> 6;
    const int lane = tid & 63;
    const int li   = lane & 15;
    const int quad = lane >> 4;

    const int m0    = blockIdx.y * 64;
    const int nbase = blockIdx.x * 256 + wave * 64;   // multiple of 64

    f32x4 acc[4][4];
    #pragma unroll
    for (int rf = 0; rf < 4; ++rf)
        #pragma unroll
        for (int t = 0; t < 4; ++t) acc[rf][t] = f32x4{0.f, 0.f, 0.f, 0.f};

    const __hip_bfloat16* xp = xb + (size_t)(m0 + li) * Ee + quad * 8;
    const __hip_bfloat16* wp = wb + (size_t)(nbase + li) * Ee + quad * 8;

    for (int k0 = 0; k0 < Ee; k0 += 32) {
        bf16x8 a[4], bfr[4];
        #pragma unroll
        for (int rf = 0; rf < 4; ++rf) a[rf]  = ldg_frag(xp + rf * 16 * Ee + k0);
        #pragma unroll
        for (int t = 0; t < 4; ++t)    bfr[t] = ldg_frag(wp + t * 16 * Ee + k0);
        #pragma unroll
        for (int rf = 0; rf < 4; ++rf)
            #pragma unroll
            for (int t = 0; t < 4; ++t)
                acc[rf][t] = __builtin_amdgcn_mfma_f32_16x16x32_bf16(
                    a[rf], bfr[t], acc[rf][t], 0, 0, 0);
    }

    // epilogue. C layout: col = li, row = quad*4 + reg.
    const int mat = nbase >> 9;        // 0=Q 1=K 2=V (uniform per wave)
    const int nn0 = nbase & 511;
    const int bb  = m0 >> 10;          // 64-row block never straddles b
    const int sb  = m0 & 1023;
    if (mat == 2) {
        #pragma unroll
        for (int t = 0; t < 4; ++t) {
            int nn = nn0 + t * 16 + li;
            int h = nn >> 5, d = nn & 31;
            size_t base = ((size_t)(bb * Hh + h) * Dd + d) * 512
                        + (sb >> 5) * 16 + quad * 4;
            #pragma unroll
            for (int p = 0; p < 2; ++p) {      // rf pair (2p, 2p+1)
                u32x4 pk;
                #pragma unroll
                for (int r = 0; r < 4; ++r)
                    pk[r] = pack_bf16(acc[2*p][t][r], acc[2*p+1][t][r]);
                *reinterpret_cast<u32x4*>(Vt32 + base + (size_t)p * 16) = pk;
            }
        }
    } else {
        __hip_bfloat16* dst = (mat == 0) ? Qs : Kh;
        const float sc = (mat == 0) ? QSCALE : 1.0f;
        #pragma unroll
        for (int rf = 0; rf < 4; ++rf) {
            const int srow = sb + rf * 16 + quad * 4;
            #pragma unroll
            for (int t = 0; t < 4; ++t) {
                int nn = nn0 + t * 16 + li;
                int h = nn >> 5, d = nn & 31;
                size_t base = ((size_t)(bb * Hh + h) * Ss + srow) * Dd + d;
                #pragma unroll
                for (int r = 0; r < 4; r += 2) {
                    unsigned w = pack_bf16(acc[rf][t][r]     * sc,
                                           acc[rf][t][r + 1] * sc);
                    dst[base + (size_t)r * Dd] =
                        __builtin_bit_cast(__hip_bfloat16, (unsigned short)(w & 0xffffu));
                    dst[base + (size_t)(r + 1) * Dd] =
                        __builtin_bit_cast(__hip_bfloat16, (unsigned short)(w >> 16));
                }
            }
        }
    }
}

// ---------------- attention -----------------------------------------------
// grid 1024; (b,h) = blockIdx&127 (XCD-local), ib = blockIdx>>7.
// Wave owns TWO 16-row Q strips (32 rows); j-loop steps 64.
// Per wave-iter: 2 global_load_lds (K,V quarters) + 4 Er loads (rotated
// window) for 30 MFMAs; K/V fragments come from LDS (ds_read_b128).
__global__ __launch_bounds__(256) void attn_kernel(
    const __hip_bfloat16* __restrict__ Qs,
    const __hip_bfloat16* __restrict__ Kh,
    const __hip_bfloat16* __restrict__ Vt,   // bf16 view of Vti (same bytes)
    const __hip_bfloat16* __restrict__ Er,   // [2048][32] bf16 (row 2047 pad)
    float* __restrict__ out)                 // [B][S][E] f32
{
    const int tid  = threadIdx.x;
    const int wave = tid >> 6;
    const int lane = tid & 63;
    const int li   = lane & 15;
    const int quad = lane >> 4;

    const int c  = blockIdx.x & 127;
    const int b  = c >> 4;
    const int h  = c & 15;
    const int ib = blockIdx.x >> 7;          // 0..7
    const int i0 = ib * 128 + wave * 32;     // strip A rows i0.., B rows i0+16..

    const __hip_bfloat16* Qp  = Qs + (size_t)(b * Hh + h) * Ss * Dd;
    const __hip_bfloat16* Kp  = Kh + (size_t)(b * Hh + h) * Ss * Dd;
    const unsigned*       Vp32 = reinterpret_cast<const unsigned*>(Vt)
                               + (size_t)(b * Hh + h) * Dd * 512;

    __shared__ unsigned pb_lds[4][4][16 * 20];       // 20480 B
    __shared__ __align__(16) unsigned char kvbuf[8192];  // K 4KB @0, V 4KB @4096
    unsigned* pbA0 = pb_lds[wave][0];   // strip A cols 0-31
    unsigned* pbA1 = pb_lds[wave][1];   // strip A cols 32-63
    unsigned* pbB0 = pb_lds[wave][2];   // strip B cols 0-31
    unsigned* pbB1 = pb_lds[wave][3];   // strip B cols 32-63

    const bf16x8 qfA = ldg_frag(Qp + (i0      + li) * Dd + quad * 8);
    const bf16x8 qfB = ldg_frag(Qp + (i0 + 16 + li) * Dd + quad * 8);

    // loop-invariant: bpermute byte-addresses and SOURCE-side band-half
    // selector (see R7 comments). 1 bpermute per band value.
    int addr4[4];
    bool sel[4];
    #pragma unroll
    for (int r = 0; r < 4; ++r) {
        const int row = quad * 4 + r;
        addr4[r] = (16 * quad + ((li - row + 15) & 15)) * 4;
        sel[r]   = (li + row >= 15);       // this lane is a lower-block src
    }
    const int pbw = quad * 80 + li;        // pb write base (u32)
    const int pbr = li * 20 + quad * 4;    // pb read base (16B aligned)

    // staging addresses (loop-invariant parts).
    // K quarter: lane l -> local row wave*16 + (l>>2), col-byte (l&3)*16.
    const int krow = wave * 16 + (lane >> 2);
    const int kcol8 = (lane & 3) * 8;                    // bf16 elems
    char* kdst = (char*)kvbuf + wave * 1024;
    // V quarter: lane l -> local row wave*8 + (l>>3); source col-byte is
    // XOR-swizzled so the LINEAR LDS write realizes lds[row][cb^sw]=V[row][cb].
    const int vrow = wave * 8 + (lane >> 3);
    const int vcol4 = 4 * ((lane & 7) ^ ((lane >> 3) & 7));  // u32 within row
    char* vdst = (char*)kvbuf + 4096 + wave * 1024;
    const int swz = (li & 7) << 4;       // read-side XOR (row li & li+16 alike)

    f32x4 oA0 = f32x4{0,0,0,0}, oA1 = f32x4{0,0,0,0};
    f32x4 oB0 = f32x4{0,0,0,0}, oB1 = f32x4{0,0,0,0};
    f32x4 lsA = f32x4{0,0,0,0}, lsB = f32x4{0,0,0,0};
    const f32x4 zero = f32x4{0,0,0,0};

    bf16x8 ones;
    #pragma unroll
    for (int i = 0; i < 8; ++i) ones[i] = (short)0x3F80;   // bf16 1.0

    // Er rotation peel: window slides by 64 each iter; em'=e3, e0'=e4.
    const int rb0 = 1008 - i0;               // >= 16 for all i0
    bf16x8 em = ldg_frag(Er + (rb0 - 16 + li) * Dd + quad * 8);
    bf16x8 e0 = ldg_frag(Er + (rb0      + li) * Dd + quad * 8);

    for (int j0 = 0; j0 < Ss; j0 += 64) {
        // ---- stage K (64x32) + V (32x64, interleaved) tiles into LDS ----
        stage16(Kp + (size_t)(j0 + krow) * Dd + kcol8, kdst);
        stage16(Vp32 + (size_t)vrow * 512 + (j0 >> 1) + vcol4, vdst);

        // ---- Er loads (new window rows; overlap staging latency) ----
        const int rb = j0 - i0 + 1008;
        bf16x8 e1 = ldg_frag(Er + (rb + 16 + li) * Dd + quad * 8);
        bf16x8 e2 = ldg_frag(Er + (rb + 32 + li) * Dd + quad * 8);
        bf16x8 e3 = ldg_frag(Er + (rb + 48 + li) * Dd + quad * 8);
        bf16x8 e4 = ldg_frag(Er + (rb + 64 + li) * Dd + quad * 8);

        // implicit s_waitcnt vmcnt(0) lgkmcnt(0) + s_barrier: every wave's
        // staging loads have landed before anyone reads the tiles.
        __syncthreads();

        // ---- K/V fragments from LDS ----
        const char* Kb = (const char*)kvbuf;
        const char* Vb = (const char*)kvbuf + 4096;
        bf16x8 k0 = *reinterpret_cast<const bf16x8*>(Kb + (     li) * 64 + quad * 16);
        bf16x8 k1 = *reinterpret_cast<const bf16x8*>(Kb + (16 + li) * 64 + quad * 16);
        bf16x8 k2 = *reinterpret_cast<const bf16x8*>(Kb + (32 + li) * 64 + quad * 16);
        bf16x8 k3 = *reinterpret_cast<const bf16x8*>(Kb + (48 + li) * 64 + quad * 16);
        bf16x8 v0 = *reinterpret_cast<const bf16x8*>(Vb + (     li) * 128 + ((     quad * 16) ^ swz));
        bf16x8 v1 = *reinterpret_cast<const bf16x8*>(Vb + (16 + li) * 128 + ((     quad * 16) ^ swz));
        bf16x8 v2 = *reinterpret_cast<const bf16x8*>(Vb + (     li) * 128 + ((64 + quad * 16) ^ swz));
        bf16x8 v3 = *reinterpret_cast<const bf16x8*>(Vb + (16 + li) * 128 + ((64 + quad * 16) ^ swz));

        // ================= strip A (rows i0..i0+15) =================
        {
            __builtin_amdgcn_s_setprio(1);
            f32x4 s0 = __builtin_amdgcn_mfma_f32_16x16x32_bf16(qfA, k0, zero, 0, 0, 0);
            f32x4 s1 = __builtin_amdgcn_mfma_f32_16x16x32_bf16(qfA, k1, zero, 0, 0, 0);
            f32x4 s2 = __builtin_amdgcn_mfma_f32_16x16x32_bf16(qfA, k2, zero, 0, 0, 0);
            f32x4 s3 = __builtin_amdgcn_mfma_f32_16x16x32_bf16(qfA, k3, zero, 0, 0, 0);
            f32x4 q0 = __builtin_amdgcn_mfma_f32_16x16x32_bf16(qfA, e0, zero, 0, 0, 0);
            f32x4 q1 = __builtin_amdgcn_mfma_f32_16x16x32_bf16(qfA, e1, zero, 0, 0, 0);
            f32x4 q2 = __builtin_amdgcn_mfma_f32_16x16x32_bf16(qfA, e2, zero, 0, 0, 0);
            f32x4 q3 = __builtin_amdgcn_mfma_f32_16x16x32_bf16(qfA, e3, zero, 0, 0, 0);
            f32x4 q4 = __builtin_amdgcn_mfma_f32_16x16x32_bf16(qfA, e4, zero, 0, 0, 0);
            __builtin_amdgcn_s_setprio(0);
            float p0[4], p1[4], p2[4], p3[4];
            #pragma unroll
            for (int r = 0; r < 4; ++r) {
                float m0 = sel[r] ? q0[r] : q1[r];
                float m1 = sel[r] ? q1[r] : q2[r];
                float m2 = sel[r] ? q2[r] : q3[r];
                float m3 = sel[r] ? q3[r] : q4[r];
                p0[r] = EXP2F(s0[r] + bperm_f(addr4[r], m0));
                p1[r] = EXP2F(s1[r] + bperm_f(addr4[r], m1));
                p2[r] = EXP2F(s2[r] + bperm_f(addr4[r], m2));
                p3[r] = EXP2F(s3[r] + bperm_f(addr4[r], m3));
            }
            #pragma unroll
            for (int r = 0; r < 4; ++r) {
                pbA0[pbw + 20 * r] = pack_bf16(p0[r], p1[r]);
                pbA1[pbw + 20 * r] = pack_bf16(p2[r], p3[r]);
            }
            bf16x8 pf0 = *reinterpret_cast<const bf16x8*>(&pbA0[pbr]);
            bf16x8 pf1 = *reinterpret_cast<const bf16x8*>(&pbA1[pbr]);
            __builtin_amdgcn_s_setprio(1);
            oA0 = __builtin_amdgcn_mfma_f32_16x16x32_bf16(pf0, v0, oA0, 0, 0, 0);
            oA1 = __builtin_amdgcn_mfma_f32_16x16x32_bf16(pf0, v1, oA1, 0, 0, 0);
            oA0 = __builtin_amdgcn_mfma_f32_16x16x32_bf16(pf1, v2, oA0, 0, 0, 0);
            oA1 = __builtin_amdgcn_mfma_f32_16x16x32_bf16(pf1, v3, oA1, 0, 0, 0);
            lsA = __builtin_amdgcn_mfma_f32_16x16x32_bf16(pf0, ones, lsA, 0, 0, 0);
            lsA = __builtin_amdgcn_mfma_f32_16x16x32_bf16(pf1, ones, lsA, 0, 0, 0);
            __builtin_amdgcn_s_setprio(0);
        }

        // ================= strip B (rows i0+16..i0+31) ==============
        // strip B's band block n == strip A's block n-1: uses em,e0..e3.
        {
            __builtin_amdgcn_s_setprio(1);
            f32x4 s0 = __builtin_amdgcn_mfma_f32_16x16x32_bf16(qfB, k0, zero, 0, 0, 0);
            f32x4 s1 = __builtin_amdgcn_mfma_f32_16x16x32_bf16(qfB, k1, zero, 0, 0, 0);
            f32x4 s2 = __builtin_amdgcn_mfma_f32_16x16x32_bf16(qfB, k2, zero, 0, 0, 0);
            f32x4 s3 = __builtin_amdgcn_mfma_f32_16x16x32_bf16(qfB, k3, zero, 0, 0, 0);
            f32x4 q0 = __builtin_amdgcn_mfma_f32_16x16x32_bf16(qfB, em, zero, 0, 0, 0);
            f32x4 q1 = __builtin_amdgcn_mfma_f32_16x16x32_bf16(qfB, e0, zero, 0, 0, 0);
            f32x4 q2 = __builtin_amdgcn_mfma_f32_16x16x32_bf16(qfB, e1, zero, 0, 0, 0);
            f32x4 q3 = __builtin_amdgcn_mfma_f32_16x16x32_bf16(qfB, e2, zero, 0, 0, 0);
            f32x4 q4 = __builtin_amdgcn_mfma_f32_16x16x32_bf16(qfB, e3, zero, 0, 0, 0);
            __builtin_amdgcn_s_setprio(0);
            float p0[4], p1[4], p2[4], p3[4];
            #pragma unroll
            for (int r = 0; r < 4; ++r) {
                float m0 = sel[r] ? q0[r] : q1[r];
                float m1 = sel[r] ? q1[r] : q2[r];
                float m2 = sel[r] ? q2[r] : q3[r];
                float m3 = sel[r] ? q3[r] : q4[r];
                p0[r] = EXP2F(s0[r] + bperm_f(addr4[r], m0));
                p1[r] = EXP2F(s1[r] + bperm_f(addr4[r], m1));
                p2[r] = EXP2F(s2[r] + bperm_f(addr4[r], m2));
                p3[r] = EXP2F(s3[r] + bperm_f(addr4[r], m3));
            }
            #pragma unroll
            for (int r = 0; r < 4; ++r) {
                pbB0[pbw + 20 * r] = pack_bf16(p0[r], p1[r]);
                pbB1[pbw + 20 * r] = pack_bf16(p2[r], p3[r]);
            }
            bf16x8 pf0 = *reinterpret_cast<const bf16x8*>(&pbB0[pbr]);
            bf16x8 pf1 = *reinterpret_cast<const bf16x8*>(&pbB1[pbr]);
            __builtin_amdgcn_s_setprio(1);
            oB0 = __builtin_amdgcn_mfma_f32_16x16x32_bf16(pf0, v0, oB0, 0, 0, 0);
            oB1 = __builtin_amdgcn_mfma_f32_16x16x32_bf16(pf0, v1, oB1, 0, 0, 0);
            oB0 = __builtin_amdgcn_mfma_f32_16x16x32_bf16(pf1, v2, oB0, 0, 0, 0);
            oB1 = __builtin_amdgcn_mfma_f32_16x16x32_bf16(pf1, v3, oB1, 0, 0, 0);
            lsB = __builtin_amdgcn_mfma_f32_16x16x32_bf16(pf0, ones, lsB, 0, 0, 0);
            lsB = __builtin_amdgcn_mfma_f32_16x16x32_bf16(pf1, ones, lsB, 0, 0, 0);
            __builtin_amdgcn_s_setprio(0);
        }

        // rotate Er window; keep buffer safe for next iter's staging.
        em = e3;
        e0 = e4;
        __syncthreads();
    }

    // ones-MFMA accumulated exact row sums in the same C layout as oA/oB.
    #pragma unroll
    for (int r = 0; r < 4; ++r) {
        lsA[r] = 1.0f / lsA[r];
        lsB[r] = 1.0f / lsB[r];
    }
    #pragma unroll
    for (int r = 0; r < 4; ++r) {
        const int srowA = i0 + quad * 4 + r;
        float* opA = out + ((size_t)b * Ss + srowA) * Ee + h * Dd;
        opA[li]      = oA0[r] * lsA[r];
        opA[16 + li] = oA1[r] * lsA[r];
        float* opB = opA + 16 * Ee;          // srowA + 16
        opB[li]      = oB0[r] * lsB[r];
        opB[16 + li] = oB1[r] * lsB[r];
    }
}

extern "C" void kernel_launch(void* const* d_in, const int* in_sizes, int n_in,
                              void* d_out, int out_size, void* d_ws, size_t ws_size,
                              hipStream_t stream) {
    const float* x  = (const float*)d_in[0];
    const float* Wq = (const float*)d_in[1];
    const float* Wk = (const float*)d_in[2];
    const float* Wv = (const float*)d_in[3];
    const float* Er = (const float*)d_in[4];
    float* out = (float*)d_out;

    // ws layout (bf16 elements; all offsets 16B-aligned)
    __hip_bfloat16* xb  = reinterpret_cast<__hip_bfloat16*>(d_ws);
    __hip_bfloat16* wbb = xb  + (size_t)8192 * 512;
    __hip_bfloat16* erb = wbb + (size_t)1536 * 512;
    __hip_bfloat16* Qs  = erb + 65536;                  // row 2047 = pad
    __hip_bfloat16* Kh  = Qs  + (size_t)Bb * Hh * Ss * Dd;
    __hip_bfloat16* Vt  = Kh  + (size_t)Bb * Hh * Ss * Dd;

    convert_kernel<<<4929, 256, 0, stream>>>(x, Wq, Wk, Wv, Er, xb, wbb, erb);
    proj_kernel<<<dim3(6, 128), 256, 0, stream>>>(
        xb, wbb, Qs, Kh, reinterpret_cast<unsigned*>(Vt));
    attn_kernel<<<dim3(1024), 256, 0, stream>>>(Qs, Kh, Vt, erb, out);
}